// Round 7
// baseline (469.582 us; speedup 1.0000x reference)
//
#include <hip/hip_runtime.h>
#include <hip/hip_bf16.h>
#include <math.h>

typedef float floatx4 __attribute__((ext_vector_type(4)));

#define IN_DIM 128
#define OUT_DIM 64

// ---------------------------------------------------------------------------
// VALU GEMM: z = h @ W^T (fp32 exact), bf16 z out, fp32 s_src/s_dst out.
// Block = 256 threads = 4 waves; block handles 32 nodes.
// ---------------------------------------------------------------------------
__global__ __launch_bounds__(256) void k_gemm(
    const float* __restrict__ h, const float* __restrict__ W,
    const float* __restrict__ a, __hip_bfloat16* __restrict__ z,
    float* __restrict__ s_src, float* __restrict__ s_dst, int N)
{
    __shared__ floatx4 sW[32 * 65];   // [k4][c], row stride 65 (pad)
    __shared__ floatx4 sH[32 * 33];   // [n][k4], row stride 33 (pad)

    const int tid = threadIdx.x;
    const int n0 = blockIdx.x * 32;

    const floatx4* W4 = (const floatx4*)W;
#pragma unroll
    for (int i = 0; i < 8; ++i) {
        int g = tid + 256 * i;            // 0..2047
        int c = g >> 5, k4 = g & 31;
        sW[k4 * 65 + c] = W4[g];
    }
    const floatx4* H4 = (const floatx4*)h;
#pragma unroll
    for (int i = 0; i < 4; ++i) {
        int g = tid + 256 * i;            // 0..1023
        int n = g >> 5, k4 = g & 31;
        sH[n * 33 + k4] = H4[(size_t)(n0 + n) * 32 + k4];
    }
    __syncthreads();

    const int wave = tid >> 6;
    const int c = tid & 63;

    floatx4 acc[8];
#pragma unroll
    for (int i = 0; i < 8; ++i) acc[i] = (floatx4){0.f, 0.f, 0.f, 0.f};

    for (int k4 = 0; k4 < 32; ++k4) {
        floatx4 w4 = sW[k4 * 65 + c];
#pragma unroll
        for (int i = 0; i < 8; ++i) {
            floatx4 h4 = sH[(wave * 8 + i) * 33 + k4];
            acc[i].x += h4.x * w4.x;
            acc[i].y += h4.y * w4.y;
            acc[i].z += h4.z * w4.z;
            acc[i].w += h4.w * w4.w;
        }
    }

    const float a1 = a[c];
    const float a2 = a[OUT_DIM + c];
#pragma unroll
    for (int i = 0; i < 8; ++i) {
        int n = n0 + wave * 8 + i;
        float v = (acc[i].x + acc[i].y) + (acc[i].z + acc[i].w);
        z[(size_t)n * OUT_DIM + c] = __float2bfloat16(v);
        float ps = v * a1;
        float pd = v * a2;
#pragma unroll
        for (int off = 32; off >= 1; off >>= 1) {
            ps += __shfl_xor(ps, off);
            pd += __shfl_xor(pd, off);
        }
        if (c == 0) {
            s_src[n] = ps;
            s_dst[n] = pd;
        }
    }
}

// ---------------------------------------------------------------------------
// CSR build
// ---------------------------------------------------------------------------
__global__ __launch_bounds__(256) void k_hist(const int* __restrict__ dst,
                                              int* __restrict__ counts, int E)
{
    int e = blockIdx.x * 256 + threadIdx.x;
    if (e < E) atomicAdd(&counts[dst[e]], 1);
}

__global__ __launch_bounds__(256) void k_scan1(const int* __restrict__ counts,
                                               int* __restrict__ offsets,
                                               int* __restrict__ bsum, int N)
{
    __shared__ int tmp[256];
    int tid = threadIdx.x;
    int i = blockIdx.x * 256 + tid;
    int v = (i < N) ? counts[i] : 0;
    tmp[tid] = v;
    __syncthreads();
    for (int o = 1; o < 256; o <<= 1) {
        int t = (tid >= o) ? tmp[tid - o] : 0;
        __syncthreads();
        tmp[tid] += t;
        __syncthreads();
    }
    if (i < N) offsets[i] = tmp[tid] - v;   // exclusive within block
    if (tid == 255) bsum[blockIdx.x] = tmp[255];
}

__global__ __launch_bounds__(512) void k_scan2(int* __restrict__ bsum, int nb)
{
    __shared__ int tmp[512];
    int tid = threadIdx.x;
    int v = (tid < nb) ? bsum[tid] : 0;
    tmp[tid] = v;
    __syncthreads();
    for (int o = 1; o < 512; o <<= 1) {
        int t = (tid >= o) ? tmp[tid - o] : 0;
        __syncthreads();
        tmp[tid] += t;
        __syncthreads();
    }
    if (tid < nb) bsum[tid] = tmp[tid] - v; // exclusive
}

__global__ __launch_bounds__(256) void k_scan3(int* __restrict__ offsets,
                                               const int* __restrict__ bsum,
                                               int* __restrict__ cursor, int N)
{
    int i = blockIdx.x * 256 + threadIdx.x;
    if (i < N) {
        int o = offsets[i] + bsum[blockIdx.x];
        offsets[i] = o;
        cursor[i] = o;
    }
}

// scatter edges into CSR order (src ids only; scores recomputed in k_node)
__global__ __launch_bounds__(256) void k_scatter(
    const int* __restrict__ src, const int* __restrict__ dst,
    int* __restrict__ cursor, int* __restrict__ ssort, int E)
{
    int e = blockIdx.x * 256 + threadIdx.x;
    if (e < E) {
        int s = src[e], d = dst[e];
        int pos = atomicAdd(&cursor[d], 1);
        ssort[pos] = s;
    }
}

// ---------------------------------------------------------------------------
// Per-node softmax + weighted gather of z[src], ELU epilogue.
// One wave per node, lane = output feature dim. Scores recomputed from
// s_src (0.4 MB, L2-resident) + broadcast s_dst[n]. Output fp32.
// ---------------------------------------------------------------------------
__global__ __launch_bounds__(256) void k_node(
    const int* __restrict__ offsets, const int* __restrict__ counts,
    const int* __restrict__ ssort, const float* __restrict__ s_src,
    const float* __restrict__ s_dst,
    const __hip_bfloat16* __restrict__ z, float* __restrict__ out, int N)
{
    const int lane = threadIdx.x & 63;
    const int wave = threadIdx.x >> 6;
    const int n = blockIdx.x * 4 + wave;
    if (n >= N) return;

    const int base = offsets[n];
    const int deg = counts[n];
    if (deg == 0) {                       // empty segment -> elu(0) = 0
        out[(size_t)n * OUT_DIM + lane] = 0.f;
        return;
    }

    const float sdn = s_dst[n];

    // pass 1: max of leaky_relu scores
    float mx = -INFINITY;
    for (int k = lane; k < deg; k += 64) {
        float sc = s_src[ssort[base + k]] + sdn;
        sc = sc > 0.f ? sc : 0.01f * sc;
        mx = fmaxf(mx, sc);
    }
#pragma unroll
    for (int off = 32; off >= 1; off >>= 1) mx = fmaxf(mx, __shfl_xor(mx, off));

    // pass 2: sum of exp
    float sum = 0.f;
    for (int k = lane; k < deg; k += 64) {
        float sc = s_src[ssort[base + k]] + sdn;
        sc = sc > 0.f ? sc : 0.01f * sc;
        sum += __expf(sc - mx);
    }
#pragma unroll
    for (int off = 32; off >= 1; off >>= 1) sum += __shfl_xor(sum, off);

    // pass 3: weighted accumulate of z[src] rows; broadcast (src, w) via shfl
    float acc = 0.f;
    for (int k0 = 0; k0 < deg; k0 += 64) {
        int kk = k0 + lane;
        int sv = 0;
        float ev = 0.f;
        if (kk < deg) {
            sv = ssort[base + kk];
            float sc = s_src[sv] + sdn;
            sc = sc > 0.f ? sc : 0.01f * sc;
            ev = __expf(sc - mx);
        }
        int cnt = min(64, deg - k0);
        for (int j = 0; j < cnt; ++j) {
            int s = __shfl(sv, j);
            float wgt = __shfl(ev, j);
            acc += wgt * __bfloat162float(z[(size_t)s * OUT_DIM + lane]);
        }
    }

    float r = acc / sum;                  // sum >= 1 (max-shifted)
    float o = r > 0.f ? r : expm1f(r);    // ELU, alpha=1
    out[(size_t)n * OUT_DIM + lane] = o;
}

// ---------------------------------------------------------------------------
extern "C" void kernel_launch(void* const* d_in, const int* in_sizes, int n_in,
                              void* d_out, int out_size, void* d_ws, size_t ws_size,
                              hipStream_t stream)
{
    (void)n_in; (void)out_size; (void)ws_size;

    // Doc dict order: h, src, dst, W, a. Inputs fp32/int32. OUTPUT IS FP32
    // (reference returns float32; prior rounds' bf16-output assumption was
    // the bug — "(bf16, ref=np)" in the test label refers to the reference's
    // rounding mode, not the output buffer dtype).
    const float* h  = (const float*)d_in[0];
    const int* src  = (const int*)d_in[1];
    const int* dst  = (const int*)d_in[2];
    const float* W  = (const float*)d_in[3];
    const float* a  = (const float*)d_in[4];
    const int N = in_sizes[0] / IN_DIM;
    const int E = in_sizes[1];
    float* out = (float*)d_out;

    char* wsp = (char*)d_ws;
    size_t off = 0;
    auto alloc = [&](size_t bytes) -> void* {
        void* p = wsp + off;
        off = (off + bytes + 255) & ~(size_t)255;
        return p;
    };
    __hip_bfloat16* z = (__hip_bfloat16*)alloc((size_t)N * OUT_DIM * 2);
    float* s_src = (float*)alloc((size_t)N * 4);
    float* s_dst = (float*)alloc((size_t)N * 4);
    int* counts  = (int*)alloc((size_t)N * 4);
    int* offsets = (int*)alloc((size_t)N * 4);
    int* cursor  = (int*)alloc((size_t)N * 4);
    int* bsum    = (int*)alloc(512 * 4);
    int* ssort   = (int*)alloc((size_t)E * 4);

    hipMemsetAsync(counts, 0, (size_t)N * 4, stream);

    k_gemm<<<(N + 31) / 32, 256, 0, stream>>>(h, W, a, z, s_src, s_dst, N);
    k_hist<<<(E + 255) / 256, 256, 0, stream>>>(dst, counts, E);
    const int nb1 = (N + 255) / 256;
    k_scan1<<<nb1, 256, 0, stream>>>(counts, offsets, bsum, N);
    k_scan2<<<1, 512, 0, stream>>>(bsum, nb1);
    k_scan3<<<nb1, 256, 0, stream>>>(offsets, bsum, cursor, N);
    k_scatter<<<(E + 255) / 256, 256, 0, stream>>>(src, dst, cursor, ssort, E);
    k_node<<<(N + 3) / 4, 256, 0, stream>>>(offsets, counts, ssort, s_src, s_dst, z, out, N);
}